// Round 1
// baseline (226.267 us; speedup 1.0000x reference)
//
#include <hip/hip_runtime.h>
#include <hip/hip_bf16.h>
#include <stdint.h>

// SpanMarker: out[b,n,:] = relu([S_row | E_row]) @ Wo + bo
//   where S = relu(h@Ws+bs), E = relu(h@We+be), rows gathered by span_idx.
// B=8, L=512, D=768, N=6144 (=L*12). All GEMMs bf16-MFMA, fp32 accum.

#define Bsz 8
#define Lsz 512
#define Dsz 768
#define Nsz 6144

typedef __attribute__((ext_vector_type(8))) short bf16x8;
typedef __attribute__((ext_vector_type(4))) float f32x4;

#define AS1 __attribute__((address_space(1)))
#define AS3 __attribute__((address_space(3)))

__device__ __forceinline__ void gll16(const void* g, void* l) {
    __builtin_amdgcn_global_load_lds((const AS1 unsigned int*)(uintptr_t)g,
                                     (AS3 unsigned int*)(uintptr_t)l, 16, 0, 0);
}

// ---------------- convert fp32 -> bf16 (vectorized) ----------------
__global__ __launch_bounds__(256) void cvt_f32_bf16(const float* __restrict__ in,
                                                    __hip_bfloat16* __restrict__ out,
                                                    int n4) {
    int i = blockIdx.x * 256 + threadIdx.x;
    if (i >= n4) return;
    float4 v = reinterpret_cast<const float4*>(in)[i];
    union { __hip_bfloat16 h[4]; short4 s; } u;
    u.h[0] = __float2bfloat16(v.x);
    u.h[1] = __float2bfloat16(v.y);
    u.h[2] = __float2bfloat16(v.z);
    u.h[3] = __float2bfloat16(v.w);
    reinterpret_cast<short4*>(out)[i] = u.s;
}

// ---------------- transpose + convert: in[R][C] fp32 -> out[C][R] bf16 ----------------
__global__ __launch_bounds__(256) void transpose_cvt(const float* __restrict__ in,
                                                     __hip_bfloat16* __restrict__ out,
                                                     int R, int C) {
    __shared__ float tile[32][33];
    int x = threadIdx.x & 31, y0 = threadIdx.x >> 5;           // y0: 0..7
    int cb = blockIdx.x * 32, rb = blockIdx.y * 32;
#pragma unroll
    for (int j = 0; j < 4; j++)
        tile[y0 + j * 8][x] = in[(size_t)(rb + y0 + j * 8) * C + cb + x];
    __syncthreads();
#pragma unroll
    for (int j = 0; j < 4; j++)
        out[(size_t)(cb + y0 + j * 8) * R + rb + x] = __float2bfloat16(tile[x][y0 + j * 8]);
}

// ---------------- shared MFMA tile compute: 128x128 tile, 4 waves (2x2), BK=64 ----------------
__device__ __forceinline__ void compute_tile(const __hip_bfloat16* As, const __hip_bfloat16* Bs,
                                             int lane, int wr, int wc, f32x4 (&acc)[4][4]) {
#pragma unroll
    for (int kk = 0; kk < 64; kk += 32) {
        int ko = kk + 8 * (lane >> 4);
        bf16x8 af[4], bfr[4];
#pragma unroll
        for (int mf = 0; mf < 4; mf++)
            af[mf] = *(const bf16x8*)&As[(wr * 64 + mf * 16 + (lane & 15)) * 64 + ko];
#pragma unroll
        for (int nf = 0; nf < 4; nf++)
            bfr[nf] = *(const bf16x8*)&Bs[(wc * 64 + nf * 16 + (lane & 15)) * 64 + ko];
#pragma unroll
        for (int mf = 0; mf < 4; mf++)
#pragma unroll
            for (int nf = 0; nf < 4; nf++)
                acc[mf][nf] = __builtin_amdgcn_mfma_f32_16x16x32_bf16(af[mf], bfr[nf], acc[mf][nf], 0, 0, 0);
    }
}

// ---------------- GEMM1: C[M][768] = relu(A[M][768] @ Bt[768][768]^T + bias), bf16 out ----------------
// A row-major [M][K=768]; Bt is B transposed: Bt[n][k]. Output bf16 [M][768].
__global__ __launch_bounds__(256) void gemm_relu_nt(const __hip_bfloat16* __restrict__ A,
                                                    const __hip_bfloat16* __restrict__ Bt,
                                                    const float* __restrict__ bias,
                                                    __hip_bfloat16* __restrict__ C) {
    __shared__ __hip_bfloat16 As[128 * 64];
    __shared__ __hip_bfloat16 Bs[128 * 64];
    int tid = threadIdx.x, lane = tid & 63, wave = tid >> 6;
    int wr = wave >> 1, wc = wave & 1;
    int m0 = blockIdx.x * 128, n0 = blockIdx.y * 128;
    int r = tid >> 3, c8 = (tid & 7) * 8;

    const __hip_bfloat16* ga[4];
    const __hip_bfloat16* gb[4];
#pragma unroll
    for (int i = 0; i < 4; i++) {
        ga[i] = A + (size_t)(m0 + r + i * 32) * Dsz + c8;
        gb[i] = Bt + (size_t)(n0 + r + i * 32) * Dsz + c8;
    }
    f32x4 acc[4][4];
#pragma unroll
    for (int mf = 0; mf < 4; mf++)
#pragma unroll
        for (int nf = 0; nf < 4; nf++) acc[mf][nf] = (f32x4){0.f, 0.f, 0.f, 0.f};

    for (int kt = 0; kt < Dsz; kt += 64) {
#pragma unroll
        for (int i = 0; i < 4; i++) gll16(ga[i] + kt, &As[(i * 256 + tid) * 8]);
#pragma unroll
        for (int i = 0; i < 4; i++) gll16(gb[i] + kt, &Bs[(i * 256 + tid) * 8]);
        __syncthreads();
        compute_tile(As, Bs, lane, wr, wc, acc);
        __syncthreads();
    }

#pragma unroll
    for (int mf = 0; mf < 4; mf++) {
        int r0 = m0 + wr * 64 + mf * 16 + (lane >> 4) * 4;
#pragma unroll
        for (int nf = 0; nf < 4; nf++) {
            int col = n0 + wc * 64 + nf * 16 + (lane & 15);
            float bv = bias[col];
#pragma unroll
            for (int rg = 0; rg < 4; rg++) {
                float v = acc[mf][nf][rg] + bv;
                v = v > 0.f ? v : 0.f;
                C[(size_t)(r0 + rg) * Dsz + col] = __float2bfloat16(v);
            }
        }
    }
}

// ---------------- GEMM2: gathered-A GEMM, out[49152][768] fp32 ----------------
// out[m] = S[b, idx_s] @ Wot[:, 0:768]^T + E[b, idx_e] @ Wot[:, 768:1536]^T + bo
// Wot: [768][1536] (n-major, pre-transposed Wo).
__global__ __launch_bounds__(256) void gemm_out_gather(const __hip_bfloat16* __restrict__ S,
                                                       const __hip_bfloat16* __restrict__ E,
                                                       const __hip_bfloat16* __restrict__ Wot,
                                                       const int* __restrict__ span_idx,
                                                       const float* __restrict__ bo,
                                                       float* __restrict__ out) {
    __shared__ __hip_bfloat16 As[128 * 64];
    __shared__ __hip_bfloat16 Bs[128 * 64];
    int tid = threadIdx.x, lane = tid & 63, wave = tid >> 6;
    int wr = wave >> 1, wc = wave & 1;
    int mt = blockIdx.x;            // 0..383 (row tile); 48 tiles per batch
    int n0 = blockIdx.y * 128;      // output col base
    int b = mt / 48;
    int nrow0 = (mt % 48) * 128;    // span index base within batch
    int r = tid >> 3, c8 = (tid & 7) * 8;

    const __hip_bfloat16* gaS[4];
    const __hip_bfloat16* gaE[4];
    const __hip_bfloat16* gb[4];
#pragma unroll
    for (int i = 0; i < 4; i++) {
        int n = nrow0 + r + i * 32;
        int is = span_idx[(size_t)(b * Nsz + n) * 2 + 0];
        int ie = span_idx[(size_t)(b * Nsz + n) * 2 + 1];
        gaS[i] = S + (size_t)(b * Lsz + is) * Dsz + c8;
        gaE[i] = E + (size_t)(b * Lsz + ie) * Dsz + c8;
        gb[i] = Wot + (size_t)(n0 + r + i * 32) * (2 * Dsz) + c8;
    }
    f32x4 acc[4][4];
#pragma unroll
    for (int mf = 0; mf < 4; mf++)
#pragma unroll
        for (int nf = 0; nf < 4; nf++) acc[mf][nf] = (f32x4){0.f, 0.f, 0.f, 0.f};

    // S-half: global k in [0,768)
    for (int kt = 0; kt < Dsz; kt += 64) {
#pragma unroll
        for (int i = 0; i < 4; i++) gll16(gaS[i] + kt, &As[(i * 256 + tid) * 8]);
#pragma unroll
        for (int i = 0; i < 4; i++) gll16(gb[i] + kt, &Bs[(i * 256 + tid) * 8]);
        __syncthreads();
        compute_tile(As, Bs, lane, wr, wc, acc);
        __syncthreads();
    }
    // E-half: global k in [768,1536)
    for (int kt = 0; kt < Dsz; kt += 64) {
#pragma unroll
        for (int i = 0; i < 4; i++) gll16(gaE[i] + kt, &As[(i * 256 + tid) * 8]);
#pragma unroll
        for (int i = 0; i < 4; i++) gll16(gb[i] + Dsz + kt, &Bs[(i * 256 + tid) * 8]);
        __syncthreads();
        compute_tile(As, Bs, lane, wr, wc, acc);
        __syncthreads();
    }

    int row_base = mt * 128 + wr * 64;
#pragma unroll
    for (int mf = 0; mf < 4; mf++) {
        int r0 = row_base + mf * 16 + (lane >> 4) * 4;
#pragma unroll
        for (int nf = 0; nf < 4; nf++) {
            int col = n0 + wc * 64 + nf * 16 + (lane & 15);
            float bv = bo[col];
#pragma unroll
            for (int rg = 0; rg < 4; rg++)
                out[(size_t)(r0 + rg) * Dsz + col] = acc[mf][nf][rg] + bv;
        }
    }
}

extern "C" void kernel_launch(void* const* d_in, const int* in_sizes, int n_in,
                              void* d_out, int out_size, void* d_ws, size_t ws_size,
                              hipStream_t stream) {
    const float* h        = (const float*)d_in[0];
    const int*   span_idx = (const int*)d_in[1];
    const float* Ws       = (const float*)d_in[2];
    const float* bs       = (const float*)d_in[3];
    const float* We       = (const float*)d_in[4];
    const float* be       = (const float*)d_in[5];
    const float* Wo       = (const float*)d_in[6];
    const float* bo       = (const float*)d_in[7];
    float* out            = (float*)d_out;

    // workspace layout (bf16): hb[4096*768] | Wst[768*768] | Wet[768*768] | Wot[768*1536] | S | E
    __hip_bfloat16* hb  = (__hip_bfloat16*)d_ws;
    __hip_bfloat16* Wst = hb + (size_t)Bsz * Lsz * Dsz;
    __hip_bfloat16* Wet = Wst + (size_t)Dsz * Dsz;
    __hip_bfloat16* Wot = Wet + (size_t)Dsz * Dsz;
    __hip_bfloat16* Sb  = Wot + (size_t)Dsz * 2 * Dsz;
    __hip_bfloat16* Eb  = Sb + (size_t)Bsz * Lsz * Dsz;
    // total: ~23.6 MB of d_ws

    // h -> bf16
    cvt_f32_bf16<<<(Bsz * Lsz * Dsz / 4 + 255) / 256, 256, 0, stream>>>(h, hb, Bsz * Lsz * Dsz / 4);
    // weights -> transposed bf16 (so MFMA B-fragments are contiguous along K)
    transpose_cvt<<<dim3(Dsz / 32, Dsz / 32), 256, 0, stream>>>(Ws, Wst, Dsz, Dsz);
    transpose_cvt<<<dim3(Dsz / 32, Dsz / 32), 256, 0, stream>>>(We, Wet, Dsz, Dsz);
    transpose_cvt<<<dim3(Dsz / 32, 2 * Dsz / 32), 256, 0, stream>>>(Wo, Wot, 2 * Dsz, Dsz);

    // S = relu(h@Ws+bs), E = relu(h@We+be)   (M=4096, N=768, K=768)
    gemm_relu_nt<<<dim3(Bsz * Lsz / 128, Dsz / 128), 256, 0, stream>>>(hb, Wst, bs, Sb);
    gemm_relu_nt<<<dim3(Bsz * Lsz / 128, Dsz / 128), 256, 0, stream>>>(hb, Wet, be, Eb);

    // out = gather(S)@Wo_top + gather(E)@Wo_bot + bo   (M=49152, N=768, K=1536)
    gemm_out_gather<<<dim3(Bsz * Nsz / 128, Dsz / 128), 256, 0, stream>>>(Sb, Eb, Wot, span_idx, bo, out);
}

// Round 2
// 101.033 us; speedup vs baseline: 2.2395x; 2.2395x over previous
//
#include <hip/hip_runtime.h>
#include <hip/hip_bf16.h>
#include <stdint.h>

// SpanMarker, algebraically collapsed:
//   P1 = relu(h@Ws+bs) @ Wo[:D]   (per token, B*L=4096 rows)
//   P2 = relu(h@We+be) @ Wo[D:]
//   out[b,n] = P1[b, is] + P2[b, ie] + bo      (pure gather-add, 151 MB write)
// B=8, L=512, D=768, N=6144.

#define Bsz 8
#define Lsz 512
#define Dsz 768
#define Nsz 6144
#define Mrows (Bsz * Lsz)        // 4096

typedef __attribute__((ext_vector_type(8))) short bf16x8;
typedef __attribute__((ext_vector_type(4))) float f32x4;

#define AS1 __attribute__((address_space(1)))
#define AS3 __attribute__((address_space(3)))

__device__ __forceinline__ void gll16(const void* g, void* l) {
    __builtin_amdgcn_global_load_lds((const AS1 unsigned int*)(uintptr_t)g,
                                     (AS3 unsigned int*)(uintptr_t)l, 16, 0, 0);
}

// ---------------- convert fp32 -> bf16 (vectorized) ----------------
__global__ __launch_bounds__(256) void cvt_f32_bf16(const float* __restrict__ in,
                                                    __hip_bfloat16* __restrict__ out,
                                                    int n4) {
    int i = blockIdx.x * 256 + threadIdx.x;
    if (i >= n4) return;
    float4 v = reinterpret_cast<const float4*>(in)[i];
    union { __hip_bfloat16 h[4]; short4 s; } u;
    u.h[0] = __float2bfloat16(v.x);
    u.h[1] = __float2bfloat16(v.y);
    u.h[2] = __float2bfloat16(v.z);
    u.h[3] = __float2bfloat16(v.w);
    reinterpret_cast<short4*>(out)[i] = u.s;
}

// ---------------- transpose + convert: in[R][C] fp32 -> out[C][R] bf16 ----------------
__global__ __launch_bounds__(256) void transpose_cvt(const float* __restrict__ in,
                                                     __hip_bfloat16* __restrict__ out,
                                                     int R, int C) {
    __shared__ float tile[32][33];
    int x = threadIdx.x & 31, y0 = threadIdx.x >> 5;
    int cb = blockIdx.x * 32, rb = blockIdx.y * 32;
#pragma unroll
    for (int j = 0; j < 4; j++)
        tile[y0 + j * 8][x] = in[(size_t)(rb + y0 + j * 8) * C + cb + x];
    __syncthreads();
#pragma unroll
    for (int j = 0; j < 4; j++)
        out[(size_t)(cb + y0 + j * 8) * R + rb + x] = __float2bfloat16(tile[x][y0 + j * 8]);
}

// ---------------- shared MFMA tile compute: 128x128 tile, 4 waves (2x2), BK=64 ----------------
__device__ __forceinline__ void compute_tile(const __hip_bfloat16* As, const __hip_bfloat16* Bs,
                                             int lane, int wr, int wc, f32x4 (&acc)[4][4]) {
#pragma unroll
    for (int kk = 0; kk < 64; kk += 32) {
        int ko = kk + 8 * (lane >> 4);
        bf16x8 af[4], bfr[4];
#pragma unroll
        for (int mf = 0; mf < 4; mf++)
            af[mf] = *(const bf16x8*)&As[(wr * 64 + mf * 16 + (lane & 15)) * 64 + ko];
#pragma unroll
        for (int nf = 0; nf < 4; nf++)
            bfr[nf] = *(const bf16x8*)&Bs[(wc * 64 + nf * 16 + (lane & 15)) * 64 + ko];
#pragma unroll
        for (int mf = 0; mf < 4; mf++)
#pragma unroll
            for (int nf = 0; nf < 4; nf++)
                acc[mf][nf] = __builtin_amdgcn_mfma_f32_16x16x32_bf16(af[mf], bfr[nf], acc[mf][nf], 0, 0, 0);
    }
}

// ---------------- GEMM1: SE[M][1536] = relu(hb[M][768] @ Wcat[1536][768]^T + bias_cat), bf16 ----------------
// Wcat rows 0..767 = Ws^T, 768..1535 = We^T. bias selected by column.
__global__ __launch_bounds__(256) void gemm1_relu(const __hip_bfloat16* __restrict__ A,
                                                  const __hip_bfloat16* __restrict__ Bt,
                                                  const float* __restrict__ bs,
                                                  const float* __restrict__ be,
                                                  __hip_bfloat16* __restrict__ C) {
    __shared__ __hip_bfloat16 As[128 * 64];
    __shared__ __hip_bfloat16 Bs[128 * 64];
    int tid = threadIdx.x, lane = tid & 63, wave = tid >> 6;
    int wr = wave >> 1, wc = wave & 1;
    int m0 = blockIdx.x * 128, n0 = blockIdx.y * 128;
    int r = tid >> 3, c8 = (tid & 7) * 8;

    const __hip_bfloat16* ga[4];
    const __hip_bfloat16* gb[4];
#pragma unroll
    for (int i = 0; i < 4; i++) {
        ga[i] = A + (size_t)(m0 + r + i * 32) * Dsz + c8;
        gb[i] = Bt + (size_t)(n0 + r + i * 32) * Dsz + c8;
    }
    f32x4 acc[4][4];
#pragma unroll
    for (int mf = 0; mf < 4; mf++)
#pragma unroll
        for (int nf = 0; nf < 4; nf++) acc[mf][nf] = (f32x4){0.f, 0.f, 0.f, 0.f};

    for (int kt = 0; kt < Dsz; kt += 64) {
#pragma unroll
        for (int i = 0; i < 4; i++) gll16(ga[i] + kt, &As[(i * 256 + tid) * 8]);
#pragma unroll
        for (int i = 0; i < 4; i++) gll16(gb[i] + kt, &Bs[(i * 256 + tid) * 8]);
        __syncthreads();
        compute_tile(As, Bs, lane, wr, wc, acc);
        __syncthreads();
    }

#pragma unroll
    for (int mf = 0; mf < 4; mf++) {
        int r0 = m0 + wr * 64 + mf * 16 + (lane >> 4) * 4;
#pragma unroll
        for (int nf = 0; nf < 4; nf++) {
            int col = n0 + wc * 64 + nf * 16 + (lane & 15);
            float bv = col < Dsz ? bs[col] : be[col - Dsz];
#pragma unroll
            for (int rg = 0; rg < 4; rg++) {
                float v = acc[mf][nf][rg] + bv;
                v = v > 0.f ? v : 0.f;
                C[(size_t)(r0 + rg) * (2 * Dsz) + col] = __float2bfloat16(v);
            }
        }
    }
}

// ---------------- GEMM2: P[z][M][768] = SE[:, z*768:(z+1)*768] @ Wot[:, z*768:(z+1)*768]^T, bf16 ----------------
// Wot: [768][1536] (pre-transposed Wo). No bias (bo added in gather_add).
__global__ __launch_bounds__(256) void gemm2_nt(const __hip_bfloat16* __restrict__ SE,
                                                const __hip_bfloat16* __restrict__ Wot,
                                                __hip_bfloat16* __restrict__ P) {
    __shared__ __hip_bfloat16 As[128 * 64];
    __shared__ __hip_bfloat16 Bs[128 * 64];
    int tid = threadIdx.x, lane = tid & 63, wave = tid >> 6;
    int wr = wave >> 1, wc = wave & 1;
    int m0 = blockIdx.x * 128, n0 = blockIdx.y * 128;
    int z = blockIdx.z;
    int koff = z * Dsz;
    int r = tid >> 3, c8 = (tid & 7) * 8;

    const __hip_bfloat16* ga[4];
    const __hip_bfloat16* gb[4];
#pragma unroll
    for (int i = 0; i < 4; i++) {
        ga[i] = SE + (size_t)(m0 + r + i * 32) * (2 * Dsz) + koff + c8;
        gb[i] = Wot + (size_t)(n0 + r + i * 32) * (2 * Dsz) + koff + c8;
    }
    f32x4 acc[4][4];
#pragma unroll
    for (int mf = 0; mf < 4; mf++)
#pragma unroll
        for (int nf = 0; nf < 4; nf++) acc[mf][nf] = (f32x4){0.f, 0.f, 0.f, 0.f};

    for (int kt = 0; kt < Dsz; kt += 64) {
#pragma unroll
        for (int i = 0; i < 4; i++) gll16(ga[i] + kt, &As[(i * 256 + tid) * 8]);
#pragma unroll
        for (int i = 0; i < 4; i++) gll16(gb[i] + kt, &Bs[(i * 256 + tid) * 8]);
        __syncthreads();
        compute_tile(As, Bs, lane, wr, wc, acc);
        __syncthreads();
    }

    __hip_bfloat16* Pz = P + (size_t)z * Mrows * Dsz;
#pragma unroll
    for (int mf = 0; mf < 4; mf++) {
        int r0 = m0 + wr * 64 + mf * 16 + (lane >> 4) * 4;
#pragma unroll
        for (int nf = 0; nf < 4; nf++) {
            int col = n0 + wc * 64 + nf * 16 + (lane & 15);
#pragma unroll
            for (int rg = 0; rg < 4; rg++)
                Pz[(size_t)(r0 + rg) * Dsz + col] = __float2bfloat16(acc[mf][nf][rg]);
        }
    }
}

// ---------------- gather-add: out[r] = P1[b,is] + P2[b,ie] + bo  (fp32 out) ----------------
#define GA_BLOCKS 2304
#define GA_TOT (Bsz * Nsz * 96)   // 96 chunks of 8 floats per row
__global__ __launch_bounds__(256) void gather_add(const __hip_bfloat16* __restrict__ P,
                                                  const int* __restrict__ span_idx,
                                                  const float* __restrict__ bo,
                                                  float* __restrict__ out) {
    for (int u = blockIdx.x * 256 + threadIdx.x; u < GA_TOT; u += GA_BLOCKS * 256) {
        int r = u / 96;           // global span row, 0..49151
        int d = (u % 96) * 8;     // feature offset
        int b = r / Nsz;
        int is = span_idx[2 * r];
        int ie = span_idx[2 * r + 1];
        const bf16x8 p1 = *(const bf16x8*)&P[((size_t)(b * Lsz + is)) * Dsz + d];
        const bf16x8 p2 = *(const bf16x8*)&P[((size_t)(Mrows + b * Lsz + ie)) * Dsz + d];
        float4 b0 = *(const float4*)&bo[d];
        float4 b1 = *(const float4*)&bo[d + 4];
        float4 o0, o1;
        union { unsigned int u; float f; } cv;
#define CVT(x) (cv.u = ((unsigned int)(unsigned short)(x)) << 16, cv.f)
        o0.x = CVT(p1[0]) + CVT(p2[0]) + b0.x;
        o0.y = CVT(p1[1]) + CVT(p2[1]) + b0.y;
        o0.z = CVT(p1[2]) + CVT(p2[2]) + b0.z;
        o0.w = CVT(p1[3]) + CVT(p2[3]) + b0.w;
        o1.x = CVT(p1[4]) + CVT(p2[4]) + b1.x;
        o1.y = CVT(p1[5]) + CVT(p2[5]) + b1.y;
        o1.z = CVT(p1[6]) + CVT(p2[6]) + b1.z;
        o1.w = CVT(p1[7]) + CVT(p2[7]) + b1.w;
#undef CVT
        float* op = &out[(size_t)r * Dsz + d];
        *(float4*)op = o0;
        *(float4*)(op + 4) = o1;
    }
}

extern "C" void kernel_launch(void* const* d_in, const int* in_sizes, int n_in,
                              void* d_out, int out_size, void* d_ws, size_t ws_size,
                              hipStream_t stream) {
    const float* h        = (const float*)d_in[0];
    const int*   span_idx = (const int*)d_in[1];
    const float* Ws       = (const float*)d_in[2];
    const float* bs       = (const float*)d_in[3];
    const float* We       = (const float*)d_in[4];
    const float* be       = (const float*)d_in[5];
    const float* Wo       = (const float*)d_in[6];
    const float* bo       = (const float*)d_in[7];
    float* out            = (float*)d_out;

    // workspace (bf16 elements):
    // hb[4096*768] | Wcat[1536*768] | Wot[768*1536] | SE[4096*1536] | P[2*4096*768]
    __hip_bfloat16* hb   = (__hip_bfloat16*)d_ws;
    __hip_bfloat16* Wcat = hb + (size_t)Mrows * Dsz;
    __hip_bfloat16* Wot  = Wcat + (size_t)2 * Dsz * Dsz;
    __hip_bfloat16* SE   = Wot + (size_t)Dsz * 2 * Dsz;
    __hip_bfloat16* P    = SE + (size_t)Mrows * 2 * Dsz;
    // total ~36.2 MB

    // h -> bf16
    cvt_f32_bf16<<<(Mrows * Dsz / 4 + 255) / 256, 256, 0, stream>>>(h, hb, Mrows * Dsz / 4);
    // Ws^T -> Wcat rows [0,768), We^T -> Wcat rows [768,1536)
    transpose_cvt<<<dim3(Dsz / 32, Dsz / 32), 256, 0, stream>>>(Ws, Wcat, Dsz, Dsz);
    transpose_cvt<<<dim3(Dsz / 32, Dsz / 32), 256, 0, stream>>>(We, Wcat + (size_t)Dsz * Dsz, Dsz, Dsz);
    // Wo^T: in [1536][768] -> out [768][1536]
    transpose_cvt<<<dim3(Dsz / 32, 2 * Dsz / 32), 256, 0, stream>>>(Wo, Wot, 2 * Dsz, Dsz);

    // SE = relu(h @ [Ws|We] + [bs|be])   (M=4096, N=1536, K=768)
    gemm1_relu<<<dim3(Mrows / 128, 2 * Dsz / 128), 256, 0, stream>>>(hb, Wcat, bs, be, SE);

    // P[z] = SE[:, z-half] @ Wo[z-half]   (M=4096, N=768, K=768) x2
    gemm2_nt<<<dim3(Mrows / 128, Dsz / 128, 2), 256, 0, stream>>>(SE, Wot, P);

    // out[b,n] = P1[b,is] + P2[b,ie] + bo
    gather_add<<<GA_BLOCKS, 256, 0, stream>>>(P, span_idx, bo, out);
}